// Round 17
// baseline (88.008 us; speedup 1.0000x reference)
//
#include <hip/hip_runtime.h>

// PlaceCellNetwork forward: out = softmax(tanh([x,1] @ Wh^T + bh + prev @ Wf) @ Wo^T + bo)
// B=4M, IN=2, HID=20, OUT=10.
//
// R17 = R16 champion (73.9us) + DUPLICATED (w,w) WEIGHT PAIRS.
// Unexplained: VALUBusy 38% = 28us vs hand-counted ~17us body. Suspect:
// R6's non-duplicated scalar weights force v_mov (w,w) pair materialization
// for every v_pk_fma_f32 source (~500 uses/thread -> ~1000 movs -> ~12us
// kernel-wide = the gap). Fix: R3-style duplicated layout -- uniform f32x2
// weight reads compile to s_load_dwordx2 -> SGPR pair -> direct VOP3P
// source, zero movs. Single-variable change vs R16.
// Predict: VALUBusy -> ~25%, dur -> 62-68us; if VALU drops but dur doesn't,
// compute-additivity is falsified -> roofline next round.
//
// Math (verified absmax 2e-3 since R3):
//   a'' = 2*log2e*(Wh x + bh + Wf^T prev);  r = rcp(1+2^a'')
//   l'  = log2e*(bo+rowsum(Wo)) - 2*log2e*Wo . r ;  out = 2^l' / sum(2^l')

#define HID 20
#define OUT 10
#define RPB 512                 // rows per block (4 waves x 128 rows)
#define RPW 128                 // rows per wave
#define WSLAB (RPW * OUT)       // 1280 words = 5120 B per wave region

typedef float f32x2 __attribute__((ext_vector_type(2)));
typedef float f32x4 __attribute__((ext_vector_type(4)));
typedef float __attribute__((address_space(1))) as1f;
typedef float __attribute__((address_space(3))) as3f;

__device__ __forceinline__ float fast_rcp(float x) { return __builtin_amdgcn_rcpf(x); }
__device__ __forceinline__ float fast_exp2(float x) { return __builtin_amdgcn_exp2f(x); }

#define EACH10(F) F(0) F(1) F(2) F(3) F(4) F(5) F(6) F(7) F(8) F(9)
#define PIN(v) asm volatile("" : "+v"(v))
#define LD2(p) (*reinterpret_cast<const f32x2*>(p))

// ---- weight repack: DUPLICATED (w,w) pairs, 48 floats per hidden unit ----
// per-i block at ws[48*i]:
//   [0:1]=(S*Wh[i][0])x2  [2:3]=(S*Wh[i][1])x2  [4:5]=(S*(Wh[i][2]+bh[i]))x2
//   [6:7]=pad  [8+2o]=(S*Wf[o][i])x2  [28+2o]=(-S*Wo[o][i])x2
// ws[960+2o] = (L*(bo[o]+sum_i Wo[o][i]))x2 ;  S=2*log2e, L=log2e
__global__ void repack_kernel(const float* __restrict__ Wh, const float* __restrict__ bh,
                              const float* __restrict__ Wo, const float* __restrict__ bo,
                              const float* __restrict__ Wf, float* __restrict__ ws) {
    const float S = 2.8853900817779268f;  // 2*log2(e)
    const float L = 1.4426950408889634f;  // log2(e)
    int t = threadIdx.x;
    if (t < HID) {
        float* b = ws + 48 * t;
        float w0 = S * Wh[3 * t + 0];
        float w1 = S * Wh[3 * t + 1];
        float wb = S * (Wh[3 * t + 2] + bh[t]);
        b[0] = w0; b[1] = w0;
        b[2] = w1; b[3] = w1;
        b[4] = wb; b[5] = wb;
        b[6] = 0.0f; b[7] = 0.0f;
        for (int o = 0; o < OUT; ++o) {
            float wf = S * Wf[o * HID + t];
            b[8 + 2 * o] = wf; b[9 + 2 * o] = wf;
            float wo = -S * Wo[o * HID + t];
            b[28 + 2 * o] = wo; b[29 + 2 * o] = wo;
        }
    } else if (t < HID + OUT) {
        int o = t - HID;
        float s = bo[o];
        for (int i = 0; i < HID; ++i) s += Wo[o * HID + i];
        float v = L * s;
        ws[960 + 2 * o] = v; ws[961 + 2 * o] = v;
    }
}

// ---- main kernel: R16 structure + pair-weight reads ----
__global__ __launch_bounds__(256, 8) void pcn_kernel(
    const float* __restrict__ x, const float* __restrict__ prev,
    const float* __restrict__ w, float* __restrict__ out, long B) {
    __shared__ float lds[4 * WSLAB];     // 20480 B -> 8 blocks/CU, 32 waves/CU
    const int t = threadIdx.x;
    const int wv = t >> 6, l = t & 63;

    // cohort phase-stagger (R16: +3%)
    {
        const int cohort = (int)((blockIdx.x >> 8) & 7);
#pragma unroll 1
        for (int i = 0; i < cohort; ++i) __builtin_amdgcn_s_sleep(8);
    }

    const long wrow = (long)blockIdx.x * RPB + (long)RPW * wv;
    const long rem = B - wrow;
    if (rem <= 0) return;
    const int Vw = (rem < RPW) ? (int)rem : RPW;
    float* slab = lds + WSLAB * wv;

    // stage own 128-row span: 5x global_load_lds (1KB each)
    const float* tsrc = prev + wrow * OUT;
    if (Vw == RPW) {
#pragma unroll
        for (int k = 0; k < 5; ++k) {
            __builtin_amdgcn_global_load_lds(
                (const as1f*)(tsrc + 4 * (64 * k + l)),
                (as3f*)(slab + 256 * k), 16, 0, 0);
        }
    } else {
        for (int f = l; f < Vw * OUT; f += 64) slab[f] = tsrc[f];
    }

    // x loads under DMA latency
    const bool aok = l < Vw;
    const bool bok = (64 + l) < Vw;
    f32x2 xa = {0.0f, 0.0f}, xb = {0.0f, 0.0f};
    if (aok) xa = *reinterpret_cast<const f32x2*>(x + 2 * (wrow + l));
    if (bok) xb = *reinterpret_cast<const f32x2*>(x + 2 * (wrow + 64 + l));

    // wait own loads; fence scheduler (rule #18)
    asm volatile("s_waitcnt vmcnt(0)" ::: "memory");
    __builtin_amdgcn_sched_barrier(0);

    const float* ra = slab + 10 * l;
    const float* rb = slab + 10 * (64 + l);
    const f32x2 x0 = {xa.x, xb.x};
    const f32x2 x1 = {xa.y, xb.y};
#define DECLP(o) f32x2 p##o = {ra[o], rb[o]}; PIN(p##o);
    EACH10(DECLP)
#undef DECLP

    // packed f32x2 compute; weights as (w,w) SGPR pairs -> direct VOP3P src
#define INITL(o) f32x2 l##o = LD2(w + 960 + 2 * o);
    EACH10(INITL)
#undef INITL
#pragma unroll
    for (int i = 0; i < HID; ++i) {
        const float* wb = w + 48 * i;
        f32x2 a = LD2(wb + 4);
        a += LD2(wb + 0) * x0;
        a += LD2(wb + 2) * x1;
#define FB(o) a += LD2(wb + 8 + 2 * o) * p##o;
        EACH10(FB)
#undef FB
        f32x2 r;
        r.x = fast_rcp(1.0f + fast_exp2(a.x));
        r.y = fast_rcp(1.0f + fast_exp2(a.y));
#define LO(o) l##o += LD2(wb + 28 + 2 * o) * r;
        EACH10(LO)
#undef LO
    }
#define EX(o) l##o.x = fast_exp2(l##o.x); l##o.y = fast_exp2(l##o.y);
    EACH10(EX)
#undef EX
    const f32x2 s = ((l0 + l1) + (l2 + l3)) + (((l4 + l5) + (l6 + l7)) + (l8 + l9));
    f32x2 rs;
    rs.x = fast_rcp(s.x);
    rs.y = fast_rcp(s.y);
#define SC(o) l##o *= rs;
    EACH10(SC)
#undef SC

    // results -> own slab (dense rows)
    __builtin_amdgcn_wave_barrier();
    if (aok) {
        f32x2* d = reinterpret_cast<f32x2*>(slab + 10 * l);
        d[0] = (f32x2){l0.x, l1.x}; d[1] = (f32x2){l2.x, l3.x};
        d[2] = (f32x2){l4.x, l5.x}; d[3] = (f32x2){l6.x, l7.x};
        d[4] = (f32x2){l8.x, l9.x};
    }
    if (bok) {
        f32x2* d = reinterpret_cast<f32x2*>(slab + 10 * (64 + l));
        d[0] = (f32x2){l0.y, l1.y}; d[1] = (f32x2){l2.y, l3.y};
        d[2] = (f32x2){l4.y, l5.y}; d[3] = (f32x2){l6.y, l7.y};
        d[4] = (f32x2){l8.y, l9.y};
    }
    __builtin_amdgcn_wave_barrier();

    // dense NT store of own span
    float* dst = out + wrow * OUT;
    if (Vw == RPW) {
#pragma unroll
        for (int k = 0; k < 5; ++k) {
            const f32x4 v = *reinterpret_cast<const f32x4*>(slab + 4 * (64 * k + l));
            __builtin_nontemporal_store(v, reinterpret_cast<f32x4*>(dst) + 64 * k + l);
        }
    } else {
        for (int f = l; f < Vw * OUT; f += 64)
            __builtin_nontemporal_store(slab[f], dst + f);
    }
}

// ---- fallback (no workspace): 1 row/thread ----
__global__ __launch_bounds__(256) void pcn_fallback(
    const float* __restrict__ x, const float* __restrict__ prev,
    const float* __restrict__ Wh, const float* __restrict__ bh,
    const float* __restrict__ Wo, const float* __restrict__ bo,
    const float* __restrict__ Wf, float* __restrict__ out, long B) {
    const long r = (long)blockIdx.x * blockDim.x + threadIdx.x;
    if (r >= B) return;
    const float x0 = x[2 * r], x1 = x[2 * r + 1];
#define DECLP(o) float p##o = prev[10 * r + o];
    EACH10(DECLP)
#undef DECLP
#define DECLL(o) float l##o = bo[o];
    EACH10(DECLL)
#undef DECLL
#pragma unroll
    for (int i = 0; i < HID; ++i) {
        float a = fmaf(Wh[3 * i], x0, fmaf(Wh[3 * i + 1], x1, Wh[3 * i + 2] + bh[i]));
#define FB(o) a = fmaf(Wf[o * HID + i], p##o, a);
        EACH10(FB)
#undef FB
        const float h = 1.0f - 2.0f * fast_rcp(1.0f + __expf(2.0f * a));
#define LO(o) l##o = fmaf(Wo[o * HID + i], h, l##o);
        EACH10(LO)
#undef LO
    }
    float m = l0;
#define MX(o) m = fmaxf(m, l##o);
    MX(1) MX(2) MX(3) MX(4) MX(5) MX(6) MX(7) MX(8) MX(9)
#undef MX
    float s = 0.0f;
#define EX(o) l##o = __expf(l##o - m); s += l##o;
    EACH10(EX)
#undef EX
    const float rs = fast_rcp(s);
#define ST(o) out[10 * r + o] = l##o * rs;
    EACH10(ST)
#undef ST
}

extern "C" void kernel_launch(void* const* d_in, const int* in_sizes, int n_in,
                              void* d_out, int out_size, void* d_ws, size_t ws_size,
                              hipStream_t stream) {
    const float* x    = (const float*)d_in[0];
    const float* prev = (const float*)d_in[1];
    const float* Wh   = (const float*)d_in[2];
    const float* bh   = (const float*)d_in[3];
    const float* Wo   = (const float*)d_in[4];
    const float* bo   = (const float*)d_in[5];
    const float* Wf   = (const float*)d_in[6];
    float* out = (float*)d_out;

    const long B = in_sizes[0] / 2;

    if (ws_size >= 980 * sizeof(float)) {
        float* ws = (float*)d_ws;
        repack_kernel<<<1, 64, 0, stream>>>(Wh, bh, Wo, bo, Wf, ws);
        const int grid = (int)((B + RPB - 1) / RPB);
        pcn_kernel<<<grid, 256, 0, stream>>>(x, prev, ws, out, B);
    } else {
        const int gb = (int)((B + 255) / 256);
        pcn_fallback<<<gb, 256, 0, stream>>>(x, prev, Wh, bh, Wo, bo, Wf, out, B);
    }
}

// Round 18
// 74.749 us; speedup vs baseline: 1.1774x; 1.1774x over previous
//
#include <hip/hip_runtime.h>

// PlaceCellNetwork forward: out = softmax(tanh([x,1] @ Wh^T + bh + prev @ Wf) @ Wo^T + bo)
// B=4M, IN=2, HID=20, OUT=10.
//
// R18 = EXACT REVERT TO R16 CHAMPION (73.9us). R17's duplicated weight
// pairs regressed (88us: doubled K$ footprint, no VALU gain) -> reverted.
// Session ledger: every structural axis tested (coalescing, caches,
// occupancy, DMA, barriers, pipelining, stagger, weight layout); champion
// combines: wave-private 128-row spans, global_load_lds DMA staging (no
// VGPR round-trip), 8 blocks/CU, free-running waves (no __syncthreads),
// NT stores, cohort phase-stagger. Memory directions proven at ~7 TB/s
// (R14 probes); residual ~25us = additive VALU exposure that resisted 6
// overlap mechanisms. If this reproduces ~74us -> ROOFLINE next round.
//
// Math (verified absmax 2e-3 since R3):
//   a'' = 2*log2e*(Wh x + bh + Wf^T prev);  r = rcp(1+2^a'')
//   l'  = log2e*(bo+rowsum(Wo)) - 2*log2e*Wo . r ;  out = 2^l' / sum(2^l')

#define HID 20
#define OUT 10
#define RPB 512                 // rows per block (4 waves x 128 rows)
#define RPW 128                 // rows per wave
#define WSLAB (RPW * OUT)       // 1280 words = 5120 B per wave region

typedef float f32x2 __attribute__((ext_vector_type(2)));
typedef float f32x4 __attribute__((ext_vector_type(4)));
typedef float __attribute__((address_space(1))) as1f;
typedef float __attribute__((address_space(3))) as3f;

__device__ __forceinline__ float fast_rcp(float x) { return __builtin_amdgcn_rcpf(x); }
__device__ __forceinline__ float fast_exp2(float x) { return __builtin_amdgcn_exp2f(x); }
__device__ __forceinline__ f32x2 sp(float s) { return (f32x2){s, s}; }

#define EACH10(F) F(0) F(1) F(2) F(3) F(4) F(5) F(6) F(7) F(8) F(9)
#define PIN(v) asm volatile("" : "+v"(v))

// ---- weight repack: scalar layout, 24 floats per hidden unit ----
// per-i block at ws[24*i]:
//   [0]=S*Wh[i][0] [1]=S*Wh[i][1] [2]=S*(Wh[i][2]+bh[i]) [3]=pad
//   [4+o]=S*Wf[o][i]   [14+o]=-S*Wo[o][i]
// ws[480+o] = L*(bo[o]+sum_i Wo[o][i]) ;  S=2*log2e, L=log2e
__global__ void repack_kernel(const float* __restrict__ Wh, const float* __restrict__ bh,
                              const float* __restrict__ Wo, const float* __restrict__ bo,
                              const float* __restrict__ Wf, float* __restrict__ ws) {
    const float S = 2.8853900817779268f;  // 2*log2(e)
    const float L = 1.4426950408889634f;  // log2(e)
    int t = threadIdx.x;
    if (t < HID) {
        float* b = ws + 24 * t;
        b[0] = S * Wh[3 * t + 0];
        b[1] = S * Wh[3 * t + 1];
        b[2] = S * (Wh[3 * t + 2] + bh[t]);
        b[3] = 0.0f;
        for (int o = 0; o < OUT; ++o) {
            b[4 + o]  = S * Wf[o * HID + t];
            b[14 + o] = -S * Wo[o * HID + t];
        }
    } else if (t < HID + OUT) {
        int o = t - HID;
        float s = bo[o];
        for (int i = 0; i < HID; ++i) s += Wo[o * HID + i];
        ws[480 + o] = L * s;
    }
}

// ---- main kernel: wave-private spans + DMA staging + NT stores + stagger ----
__global__ __launch_bounds__(256, 8) void pcn_kernel(
    const float* __restrict__ x, const float* __restrict__ prev,
    const float* __restrict__ w, float* __restrict__ out, long B) {
    __shared__ float lds[4 * WSLAB];     // 20480 B -> 8 blocks/CU, 32 waves/CU
    const int t = threadIdx.x;
    const int wv = t >> 6, l = t & 63;

    // cohort phase-stagger: blocks c, c+256, ..., c+1792 co-reside on a CU;
    // offset cohort k by k*~0.21us (s_sleep(8) ~ 512 cy) to break phase
    // lockstep. One-time cost; successors inherit offsets. (R16: +3%)
    {
        const int cohort = (int)((blockIdx.x >> 8) & 7);
#pragma unroll 1
        for (int i = 0; i < cohort; ++i) __builtin_amdgcn_s_sleep(8);
    }

    const long wrow = (long)blockIdx.x * RPB + (long)RPW * wv;  // wave's 1st row
    const long rem = B - wrow;
    if (rem <= 0) return;                       // empty tail wave
    const int Vw = (rem < RPW) ? (int)rem : RPW;
    float* slab = lds + WSLAB * wv;

    // ---- stage own 128-row span: 5x global_load_lds (1KB each, no VGPRs) ----
    const float* tsrc = prev + wrow * OUT;
    if (Vw == RPW) {
#pragma unroll
        for (int k = 0; k < 5; ++k) {
            __builtin_amdgcn_global_load_lds(
                (const as1f*)(tsrc + 4 * (64 * k + l)),   // per-lane global src
                (as3f*)(slab + 256 * k),                  // wave-uniform dest
                16, 0, 0);
        }
    } else {
        for (int f = l; f < Vw * OUT; f += 64) slab[f] = tsrc[f];  // rare tail
    }

    // ---- x loads issued under the DMA latency (dense 8B) ----
    const bool aok = l < Vw;
    const bool bok = (64 + l) < Vw;
    f32x2 xa = {0.0f, 0.0f}, xb = {0.0f, 0.0f};
    if (aok) xa = *reinterpret_cast<const f32x2*>(x + 2 * (wrow + l));
    if (bok) xb = *reinterpret_cast<const f32x2*>(x + 2 * (wrow + 64 + l));

    // ---- wait own loads; fence scheduler (compiler can't see DMA->LDS dep) ----
    asm volatile("s_waitcnt vmcnt(0)" ::: "memory");
    __builtin_amdgcn_sched_barrier(0);

    // ---- rows (wrow+l, wrow+64+l) from own slab (4-way conflict, hidden) ----
    const float* ra = slab + 10 * l;
    const float* rb = slab + 10 * (64 + l);
    const f32x2 x0 = {xa.x, xb.x};
    const f32x2 x1 = {xa.y, xb.y};
#define DECLP(o) f32x2 p##o = {ra[o], rb[o]}; PIN(p##o);
    EACH10(DECLP)
#undef DECLP

    // ---- packed f32x2 compute (verified core) ----
#define INITL(o) f32x2 l##o = sp(w[480 + o]);
    EACH10(INITL)
#undef INITL
#pragma unroll
    for (int i = 0; i < HID; ++i) {
        const float* wb = w + 24 * i;
        f32x2 a = sp(wb[2]);
        a += sp(wb[0]) * x0;
        a += sp(wb[1]) * x1;
#define FB(o) a += sp(wb[4 + o]) * p##o;
        EACH10(FB)
#undef FB
        f32x2 r;
        r.x = fast_rcp(1.0f + fast_exp2(a.x));
        r.y = fast_rcp(1.0f + fast_exp2(a.y));
#define LO(o) l##o += sp(wb[14 + o]) * r;
        EACH10(LO)
#undef LO
    }
#define EX(o) l##o.x = fast_exp2(l##o.x); l##o.y = fast_exp2(l##o.y);
    EACH10(EX)
#undef EX
    const f32x2 s = ((l0 + l1) + (l2 + l3)) + (((l4 + l5) + (l6 + l7)) + (l8 + l9));
    f32x2 rs;
    rs.x = fast_rcp(s.x);
    rs.y = fast_rcp(s.y);
#define SC(o) l##o *= rs;
    EACH10(SC)
#undef SC

    // ---- results -> own slab (dense rows); wave-internal ordering only ----
    __builtin_amdgcn_wave_barrier();
    if (aok) {
        f32x2* d = reinterpret_cast<f32x2*>(slab + 10 * l);
        d[0] = (f32x2){l0.x, l1.x}; d[1] = (f32x2){l2.x, l3.x};
        d[2] = (f32x2){l4.x, l5.x}; d[3] = (f32x2){l6.x, l7.x};
        d[4] = (f32x2){l8.x, l9.x};
    }
    if (bok) {
        f32x2* d = reinterpret_cast<f32x2*>(slab + 10 * (64 + l));
        d[0] = (f32x2){l0.y, l1.y}; d[1] = (f32x2){l2.y, l3.y};
        d[2] = (f32x2){l4.y, l5.y}; d[3] = (f32x2){l6.y, l7.y};
        d[4] = (f32x2){l8.y, l9.y};
    }
    __builtin_amdgcn_wave_barrier();

    // ---- dense NT store of own span (5x 1KB per wave) ----
    float* dst = out + wrow * OUT;
    if (Vw == RPW) {
#pragma unroll
        for (int k = 0; k < 5; ++k) {
            const f32x4 v = *reinterpret_cast<const f32x4*>(slab + 4 * (64 * k + l));
            __builtin_nontemporal_store(v, reinterpret_cast<f32x4*>(dst) + 64 * k + l);
        }
    } else {
        for (int f = l; f < Vw * OUT; f += 64)
            __builtin_nontemporal_store(slab[f], dst + f);
    }
}

// ---- fallback (no workspace): 1 row/thread ----
__global__ __launch_bounds__(256) void pcn_fallback(
    const float* __restrict__ x, const float* __restrict__ prev,
    const float* __restrict__ Wh, const float* __restrict__ bh,
    const float* __restrict__ Wo, const float* __restrict__ bo,
    const float* __restrict__ Wf, float* __restrict__ out, long B) {
    const long r = (long)blockIdx.x * blockDim.x + threadIdx.x;
    if (r >= B) return;
    const float x0 = x[2 * r], x1 = x[2 * r + 1];
#define DECLP(o) float p##o = prev[10 * r + o];
    EACH10(DECLP)
#undef DECLP
#define DECLL(o) float l##o = bo[o];
    EACH10(DECLL)
#undef DECLL
#pragma unroll
    for (int i = 0; i < HID; ++i) {
        float a = fmaf(Wh[3 * i], x0, fmaf(Wh[3 * i + 1], x1, Wh[3 * i + 2] + bh[i]));
#define FB(o) a = fmaf(Wf[o * HID + i], p##o, a);
        EACH10(FB)
#undef FB
        const float h = 1.0f - 2.0f * fast_rcp(1.0f + __expf(2.0f * a));
#define LO(o) l##o = fmaf(Wo[o * HID + i], h, l##o);
        EACH10(LO)
#undef LO
    }
    float m = l0;
#define MX(o) m = fmaxf(m, l##o);
    MX(1) MX(2) MX(3) MX(4) MX(5) MX(6) MX(7) MX(8) MX(9)
#undef MX
    float s = 0.0f;
#define EX(o) l##o = __expf(l##o - m); s += l##o;
    EACH10(EX)
#undef EX
    const float rs = fast_rcp(s);
#define ST(o) out[10 * r + o] = l##o * rs;
    EACH10(ST)
#undef ST
}

extern "C" void kernel_launch(void* const* d_in, const int* in_sizes, int n_in,
                              void* d_out, int out_size, void* d_ws, size_t ws_size,
                              hipStream_t stream) {
    const float* x    = (const float*)d_in[0];
    const float* prev = (const float*)d_in[1];
    const float* Wh   = (const float*)d_in[2];
    const float* bh   = (const float*)d_in[3];
    const float* Wo   = (const float*)d_in[4];
    const float* bo   = (const float*)d_in[5];
    const float* Wf   = (const float*)d_in[6];
    float* out = (float*)d_out;

    const long B = in_sizes[0] / 2;

    if (ws_size >= 490 * sizeof(float)) {
        float* ws = (float*)d_ws;
        repack_kernel<<<1, 64, 0, stream>>>(Wh, bh, Wo, bo, Wf, ws);
        const int grid = (int)((B + RPB - 1) / RPB);
        pcn_kernel<<<grid, 256, 0, stream>>>(x, prev, ws, out, B);
    } else {
        const int gb = (int)((B + 255) / 256);
        pcn_fallback<<<gb, 256, 0, stream>>>(x, prev, Wh, bh, Wo, bo, Wf, out, B);
    }
}